// Round 1
// baseline (174.012 us; speedup 1.0000x reference)
//
#include <hip/hip_runtime.h>

// ModuleCollect: out[i] = concat(x[i], masked_gather(x, idx[i,0..3]))
// x: [N, 256] f32, indices: [N,4] int (-1 = masked -> zeros)
// out: [N, 1280] f32
//
// One 64-lane wave per row. Each lane moves one float4 (4 floats) per
// 256-float segment: 64 lanes * 4 = 256. 5 segments per row.
// Block = 256 threads = 4 waves = 4 rows.

#define D 256
#define D4 (D / 4)        // 64 float4 per row of x
#define OUTW (5 * D)      // 1280
#define OUTW4 (OUTW / 4)  // 320
#define ROWS_PER_BLOCK 4

__global__ __launch_bounds__(256) void collect_kernel(
    const float4* __restrict__ x4,      // [N * 64] float4
    const int*    __restrict__ indices, // [N * 4]
    float4*       __restrict__ out4,    // [N * 320] float4
    int n)
{
    const int wave = threadIdx.x >> 6;           // 0..3
    const int lane = threadIdx.x & 63;           // 0..63
    const int row  = blockIdx.x * ROWS_PER_BLOCK + wave;
    if (row >= n) return;

    const float4* xrow = x4 + (long)row * D4;
    float4* orow = out4 + (long)row * OUTW4;

    // segment 0: copy own row
    orow[lane] = xrow[lane];

    // segments 1..4: gathered neighbors (masked)
    const int i0 = indices[row * 4 + 0];
    const int i1 = indices[row * 4 + 1];
    const int i2 = indices[row * 4 + 2];
    const int i3 = indices[row * 4 + 3];

    const float4 zero = make_float4(0.f, 0.f, 0.f, 0.f);

    orow[D4 * 1 + lane] = (i0 >= 0) ? x4[(long)i0 * D4 + lane] : zero;
    orow[D4 * 2 + lane] = (i1 >= 0) ? x4[(long)i1 * D4 + lane] : zero;
    orow[D4 * 3 + lane] = (i2 >= 0) ? x4[(long)i2 * D4 + lane] : zero;
    orow[D4 * 4 + lane] = (i3 >= 0) ? x4[(long)i3 * D4 + lane] : zero;
}

extern "C" void kernel_launch(void* const* d_in, const int* in_sizes, int n_in,
                              void* d_out, int out_size, void* d_ws, size_t ws_size,
                              hipStream_t stream)
{
    const float4* x4 = (const float4*)d_in[0];
    const int* indices = (const int*)d_in[1];
    float4* out4 = (float4*)d_out;

    const int n = in_sizes[0] / D;  // 100000

    dim3 block(256);
    dim3 grid((n + ROWS_PER_BLOCK - 1) / ROWS_PER_BLOCK);
    collect_kernel<<<grid, block, 0, stream>>>(x4, indices, out4, n);
}

// Round 3
// 149.831 us; speedup vs baseline: 1.1614x; 1.1614x over previous
//
#include <hip/hip_runtime.h>

// ModuleCollect: out[i] = concat(x[i], masked_gather(x, idx[i,0..3]))
// x: [N, 256] f32, indices: [N,4] int (-1 = masked -> zeros)
// out: [N, 1280] f32
//
// One 64-lane wave per row; each lane moves one float4 per 256-float
// segment (64*4 = 256). Block = 256 threads = 4 waves = 4 rows.
//
// Output stores are NON-TEMPORAL: out is 512 MB write-once data. Letting
// it stream through L2/L3 evicts x (102 MB, would otherwise stay L3-
// resident), forcing the 4x random gathers to HBM. nt stores keep x
// cached so gathers hit Infinity Cache.
//
// NOTE: __builtin_nontemporal_store requires a native vector type, not
// HIP's float4 class -> use ext_vector_type(4) float.

typedef float f32x4 __attribute__((ext_vector_type(4)));

#define D 256
#define D4 (D / 4)        // 64 f32x4 per row of x
#define OUTW (5 * D)      // 1280
#define OUTW4 (OUTW / 4)  // 320
#define ROWS_PER_BLOCK 4

__global__ __launch_bounds__(256) void collect_kernel(
    const f32x4* __restrict__ x4,      // [N * 64]
    const int*   __restrict__ indices, // [N * 4]
    f32x4*       __restrict__ out4,    // [N * 320]
    int n)
{
    const int wave = threadIdx.x >> 6;           // 0..3
    const int lane = threadIdx.x & 63;           // 0..63
    const int row  = blockIdx.x * ROWS_PER_BLOCK + wave;
    if (row >= n) return;

    const f32x4* xrow = x4 + (long)row * D4;
    f32x4* orow = out4 + (long)row * OUTW4;

    // indices are wave-uniform -> scalar loads
    const int i0 = indices[row * 4 + 0];
    const int i1 = indices[row * 4 + 1];
    const int i2 = indices[row * 4 + 2];
    const int i3 = indices[row * 4 + 3];

    const f32x4 zero = (f32x4){0.f, 0.f, 0.f, 0.f};

    // issue all loads first (ILP), then store
    f32x4 v_self = xrow[lane];
    f32x4 v0 = (i0 >= 0) ? x4[(long)i0 * D4 + lane] : zero;
    f32x4 v1 = (i1 >= 0) ? x4[(long)i1 * D4 + lane] : zero;
    f32x4 v2 = (i2 >= 0) ? x4[(long)i2 * D4 + lane] : zero;
    f32x4 v3 = (i3 >= 0) ? x4[(long)i3 * D4 + lane] : zero;

    __builtin_nontemporal_store(v_self, &orow[lane]);
    __builtin_nontemporal_store(v0, &orow[D4 * 1 + lane]);
    __builtin_nontemporal_store(v1, &orow[D4 * 2 + lane]);
    __builtin_nontemporal_store(v2, &orow[D4 * 3 + lane]);
    __builtin_nontemporal_store(v3, &orow[D4 * 4 + lane]);
}

extern "C" void kernel_launch(void* const* d_in, const int* in_sizes, int n_in,
                              void* d_out, int out_size, void* d_ws, size_t ws_size,
                              hipStream_t stream)
{
    const f32x4* x4 = (const f32x4*)d_in[0];
    const int* indices = (const int*)d_in[1];
    f32x4* out4 = (f32x4*)d_out;

    const int n = in_sizes[0] / D;  // 100000

    dim3 block(256);
    dim3 grid((n + ROWS_PER_BLOCK - 1) / ROWS_PER_BLOCK);
    collect_kernel<<<grid, block, 0, stream>>>(x4, indices, out4, n);
}